// Round 8
// baseline (630.894 us; speedup 1.0000x reference)
//
#include <hip/hip_runtime.h>
#include <hip/hip_bf16.h>
#include <stdint.h>

typedef __bf16 bf16;
typedef bf16 bf16x8 __attribute__((ext_vector_type(8)));
typedef bf16 bf16x4 __attribute__((ext_vector_type(4)));
typedef float f32x4 __attribute__((ext_vector_type(4)));

constexpr int N = 2048;   // tokens
constexpr int C = 1024;   // model dim
constexpr int H = 2048;   // hidden dim
constexpr int E = 8;      // experts
constexpr float EPS = 1.1920929e-07f;

constexpr int NBLK = 256;   // persistent blocks (all co-resident: ~26KB LDS, 8 waves)
constexpr int NTHR = 512;   // 8 waves
constexpr int BM = 128, BN = 256, BK = 32;   // proven R9 single-buffer worker
constexpr int GT = 32;

// ---------------- work-queue item counts ----------------
constexpr int G_GATE = N / GT;                          // 64
constexpr int G_RMS  = N / 8;                           // 256 (8 rows/item)
constexpr int CVT_F4 = (E * H * C + H * C) / 4;         // 4718592 f4 per pair
constexpr int CVT_ITEMS = CVT_F4 / 4096;                // 1152 (512thr x 8 f4)
constexpr int P0_ITEMS = G_GATE + G_RMS + CVT_ITEMS;    // 1472

constexpr int P1_UP = E * (N / BM) * (H / BN);          // 1024
constexpr int P1_KP = (N / BM) * (H / BN);              // 128
constexpr int P1_ITEMS = P1_UP + P1_KP + CVT_ITEMS;     // 2304 (cvt2 overlaps)

constexpr int P2_DOWN = (E * 2) * (N / BM) * (C / BN);  // 1024
constexpr int P2_VP = (N / BM) * (C / BN) * 2;          // 128
constexpr int P2_ITEMS = P2_DOWN + P2_VP;               // 1152

constexpr int P3_ITEMS = (N * C / 4) / 2048;            // 256 combine items

// ------------------------------------------------ device-scope spin barrier
// Safe because all NBLK blocks are co-resident by construction (each CU holds
// >=2 such blocks by LDS/VGPR/wave budgets; grid == 256 == CU count).
__device__ __forceinline__ void grid_barrier(int* bar, int tid) {
  __syncthreads();
  __threadfence();                       // my writes visible device-wide
  if (tid == 0) {
    atomicAdd(bar, 1);
    while (atomicAdd(bar, 0) < NBLK) __builtin_amdgcn_s_sleep(8);
  }
  __syncthreads();
  __threadfence();                       // acquire: see other blocks' writes
}

// ----------------------------------------------------- fp32->bf16 cvt item
// one item converts 4096 float4s (8/thread, stride-512) across two arrays
__device__ __forceinline__ void cvt8(const float* __restrict__ s1, bf16* __restrict__ d1,
                                     size_t n1, const float* __restrict__ s2,
                                     bf16* __restrict__ d2, int item) {
  size_t base = (size_t)item * 4096 + threadIdx.x;
  #pragma unroll
  for (int j = 0; j < 8; ++j) {
    size_t i = base + (size_t)j * 512;
    if (i < n1) {
      float4 v = ((const float4*)s1)[i];
      bf16x4 o = { (bf16)v.x, (bf16)v.y, (bf16)v.z, (bf16)v.w };
      ((bf16x4*)d1)[i] = o;
    } else {
      size_t k = i - n1;
      float4 v = ((const float4*)s2)[k];
      bf16x4 o = { (bf16)v.x, (bf16)v.y, (bf16)v.z, (bf16)v.w };
      ((bf16x4*)d2)[k] = o;
    }
  }
}

// -------------------------------------------------------------- rms item
// 8 token rows per item, one row per wave; pure-shfl reduction.
__device__ __forceinline__ void rms_item(int it, const float* __restrict__ x,
                                         bf16* __restrict__ xtb,
                                         float* __restrict__ rs2_arr) {
  const int lane = threadIdx.x & 63, wave = threadIdx.x >> 6;
  const int n = it * 8 + wave;
  const float4* xr = (const float4*)(x + (size_t)n * C);
  float4 v[4];
  float ss = 0.f;
  #pragma unroll
  for (int j = 0; j < 4; ++j) {
    v[j] = xr[j * 64 + lane];
    ss += v[j].x * v[j].x + v[j].y * v[j].y + v[j].z * v[j].z + v[j].w * v[j].w;
  }
  #pragma unroll
  for (int off = 32; off > 0; off >>= 1) ss += __shfl_xor(ss, off, 64);
  float rs1 = rsqrtf(ss * (1.f / C) + EPS);
  bf16x4* ot = (bf16x4*)(xtb + (size_t)n * C);
  #pragma unroll
  for (int j = 0; j < 4; ++j) {
    bf16x4 o = { (bf16)(v[j].x * rs1), (bf16)(v[j].y * rs1),
                 (bf16)(v[j].z * rs1), (bf16)(v[j].w * rs1) };
    ot[j * 64 + lane] = o;
  }
  if (lane == 0) {
    float m2 = ss * rs1 * rs1 * (1.f / C);   // mean(xt^2) exactly
    rs2_arr[n] = rsqrtf(m2 + EPS);
  }
}

// -------------------------------------------------------------- gate item
// 32 tokens/item, 4 per wave (8 waves). gate_w read straight from L2.
__device__ __forceinline__ void gate_item(
    int it, const float* __restrict__ x, const float* __restrict__ gate_w,
    const float* __restrict__ sgw, float* __restrict__ g,
    float* __restrict__ sgbuf, int* __restrict__ counts,
    int* __restrict__ lists, float* __restrict__ scoresums,
    float* s_scores, int* s_cnt, int* s_base,
    int* s_e1, int* s_p1, int* s_e2, int* s_p2) {
  const int tid = threadIdx.x, lane = tid & 63, wave = tid >> 6;
  if (tid < 8) { s_scores[tid] = 0.f; s_cnt[tid] = 0; }
  __syncthreads();
  const int tok0 = it * GT + wave * 4;
  for (int tt = 0; tt < 4; ++tt) {
    const int tok = tok0 + tt;
    const float* xr = x + (size_t)tok * C;
    float acc[10];
    #pragma unroll
    for (int e = 0; e < 10; e++) acc[e] = 0.f;
    #pragma unroll
    for (int k = 0; k < 16; ++k) {
      int c = k * 64 + lane;
      float xv = xr[c];
      #pragma unroll
      for (int e = 0; e < 8; e++) acc[e] = fmaf(xv, gate_w[e * 1024 + c], acc[e]);
      acc[8] = fmaf(xv, sgw[c], acc[8]);
      acc[9] = fmaf(xv, xv, acc[9]);           // sum(x^2) for self rs1
    }
    #pragma unroll
    for (int e = 0; e < 10; e++) {
      float v = acc[e];
      #pragma unroll
      for (int off = 32; off > 0; off >>= 1) v += __shfl_xor(v, off, 64);
      acc[e] = v;
    }
    if (lane == 0) {
      float rs1 = rsqrtf(acc[9] * (1.f / C) + EPS);
      float raw[9];
      #pragma unroll
      for (int e = 0; e < 9; e++) raw[e] = acc[e] * rs1;
      float m = raw[0];
      for (int e = 1; e < 8; e++) m = fmaxf(m, raw[e]);
      float sc[8], s = 0.f;
      for (int e = 0; e < 8; e++) { sc[e] = expf(raw[e] - m); s += sc[e]; }
      float inv = 1.f / s;
      for (int e = 0; e < 8; e++) sc[e] *= inv;
      int i1 = 0;
      for (int e = 1; e < 8; e++) if (sc[e] > sc[i1]) i1 = e;
      int i2 = -1;
      for (int e = 0; e < 8; e++) {
        if (e == i1) continue;
        if (i2 < 0 || sc[e] > sc[i2]) i2 = e;
      }
      float denom = sc[i1] + sc[i2] + 1e-6f;
      float* gr = g + (size_t)tok * E;
      #pragma unroll
      for (int e = 0; e < 8; e++) gr[e] = 0.f;
      gr[i1] = sc[i1] / denom;
      gr[i2] = sc[i2] / denom;
      sgbuf[tok] = 1.f / (1.f + expf(-raw[8]));
      for (int e = 0; e < 8; e++) atomicAdd(&s_scores[e], sc[e]);  // LDS
      int lt = wave * 4 + tt;
      int p1 = atomicAdd(&s_cnt[i1], 1);   // LDS
      int p2 = atomicAdd(&s_cnt[i2], 1);   // LDS
      s_e1[lt] = i1; s_p1[lt] = p1;
      s_e2[lt] = i2; s_p2[lt] = p2;
    }
  }
  __syncthreads();
  if (tid < 8) {
    s_base[tid] = atomicAdd(&counts[tid], s_cnt[tid]);   // global
    atomicAdd(&scoresums[tid], s_scores[tid]);
  }
  __syncthreads();
  if (tid < GT) {
    int tok = it * GT + tid;
    int e1 = s_e1[tid], e2 = s_e2[tid];
    lists[e1 * N + s_base[e1] + s_p1[tid]] = (tok << 1);
    lists[e2 * N + s_base[e2] + s_p2[tid]] = (tok << 1) | 1;
  }
}

// -------------------------------------------------------- MFMA GEMM worker
// proven single-buffer 128x256 8-wave loop (R9 geometry).
#define GLL(gp, lp)                                                             \
  __builtin_amdgcn_global_load_lds((__attribute__((address_space(1))) void*)(gp), \
                                   (__attribute__((address_space(3))) void*)(lp), 16, 0, 0)

__device__ __forceinline__ void mfma_loop(
    const char* pA, const char* pB0, const char* pB1,
    char* As, char* Bs, int dA, int dB, int lane,
    int kIters, int mb, int nb, f32x4 acc[4][4]) {
  const int arow = lane & 15;
  const int koff = (lane >> 4) * 16;
  for (int kt = 0; kt < kIters; ++kt) {
    GLL(pA, As + dA);
    GLL(pB0, Bs + dB);
    GLL(pB1, Bs + dB + 1024);
    pA += BK * 2; pB0 += BK * 2; pB1 += BK * 2;
    __syncthreads();
    bf16x8 a[4], b[4];
    #pragma unroll
    for (int i = 0; i < 4; ++i) {
      a[i] = *(const bf16x8*)(As + (mb + i * 16 + arow) * 64 + koff);
      b[i] = *(const bf16x8*)(Bs + (nb + i * 16 + arow) * 64 + koff);
    }
    #pragma unroll
    for (int i = 0; i < 4; ++i)
      #pragma unroll
      for (int j = 0; j < 4; ++j)
        acc[i][j] = __builtin_amdgcn_mfma_f32_16x16x32_bf16(a[i], b[j], acc[i][j], 0, 0, 0);
    __syncthreads();
  }
}

#define GEMM_VARS                                                  \
  const int tid = threadIdx.x;                                     \
  const int lane = tid & 63, wave = tid >> 6;  /* 0..7 */          \
  const int mb = (wave >> 2) * 64, nb = (wave & 3) * 64;           \
  const int sra = wave * 16 + (lane >> 2);     /* A staging row */ \
  const int srb = wave * 32 + (lane >> 2);     /* B staging row */ \
  const int scb = (lane & 3) * 16;             /* staging col bytes */\
  const int dA = wave * 1024, dB = wave * 2048;                    \
  const int col = lane & 15, quad = lane >> 4;                     \
  f32x4 acc[4][4] = {};

__device__ __forceinline__ void run_up(
    const bf16* __restrict__ xtb, const bf16* __restrict__ w1b,
    const float* __restrict__ g, const int* __restrict__ lists,
    const int* __restrict__ counts, bf16* __restrict__ hb,
    int e, int m0, int h0, char* As, char* Bs, int* toks) {
  const int cnt = counts[e];
  if (m0 >= cnt) return;
  GEMM_VARS
  if (tid < BM) toks[tid] = lists[e * N + min(m0 + tid, cnt - 1)];
  __syncthreads();
  const char* pA  = (const char*)xtb + ((size_t)(toks[sra] >> 1) * C) * 2 + scb;
  const char* pB0 = (const char*)w1b + ((size_t)e * H * C + (size_t)(h0 + srb) * C) * 2 + scb;
  const char* pB1 = pB0 + (size_t)16 * C * 2;
  mfma_loop(pA, pB0, pB1, As, Bs, dA, dB, lane, C / BK, mb, nb, acc);
  #pragma unroll
  for (int mi = 0; mi < 4; mi++) {
    #pragma unroll
    for (int r = 0; r < 4; r++) {
      int ml = mb + mi * 16 + quad * 4 + r;
      if (m0 + ml < cnt) {
        int packed = toks[ml];
        float gv = g[(size_t)(packed >> 1) * E + e];
        size_t base = (size_t)packed * H + h0 + nb;
        #pragma unroll
        for (int ni = 0; ni < 4; ni++) {
          float v = fmaxf(acc[mi][ni][r], 0.f);
          hb[base + ni * 16 + col] = (bf16)(v * v * gv);
        }
      }
    }
  }
}

__device__ __forceinline__ void run_kproj(
    const bf16* __restrict__ xtb, const bf16* __restrict__ kwb,
    const float* __restrict__ rs2, const float* __restrict__ k_b,
    bf16* __restrict__ kkb, int n0, int h0, char* As, char* Bs) {
  GEMM_VARS
  const char* pA  = (const char*)xtb + ((size_t)(n0 + sra) * C) * 2 + scb;
  const char* pB0 = (const char*)kwb + ((size_t)(h0 + srb) * C) * 2 + scb;
  const char* pB1 = pB0 + (size_t)16 * C * 2;
  mfma_loop(pA, pB0, pB1, As, Bs, dA, dB, lane, C / BK, mb, nb, acc);
  #pragma unroll
  for (int mi = 0; mi < 4; mi++) {
    #pragma unroll
    for (int r = 0; r < 4; r++) {
      int n = n0 + mb + mi * 16 + quad * 4 + r;
      float rs = rs2[n];
      #pragma unroll
      for (int ni = 0; ni < 4; ni++) {
        int h = h0 + nb + ni * 16 + col;
        float v = fmaf(acc[mi][ni][r], rs, k_b[h]);
        v = fmaxf(v, 0.f);
        kkb[(size_t)n * H + h] = (bf16)(v * v);
      }
    }
  }
}

__device__ __forceinline__ void run_down(
    const bf16* __restrict__ hb, const bf16* __restrict__ w2b,
    const int* __restrict__ lists, const int* __restrict__ counts,
    float* __restrict__ dp, int e, int ks, int m0, int c0,
    char* As, char* Bs, int* toks) {
  const int cnt = counts[e];
  if (m0 >= cnt) return;
  GEMM_VARS
  if (tid < BM) toks[tid] = lists[e * N + min(m0 + tid, cnt - 1)];
  __syncthreads();
  const size_t kofs = (size_t)ks * (H / 2) * 2;
  const char* pA  = (const char*)hb + ((size_t)toks[sra] * H) * 2 + kofs + scb;
  const char* pB0 = (const char*)w2b + ((size_t)e * C * H + (size_t)(c0 + srb) * H) * 2 + kofs + scb;
  const char* pB1 = pB0 + (size_t)16 * H * 2;
  mfma_loop(pA, pB0, pB1, As, Bs, dA, dB, lane, (H / 2) / BK, mb, nb, acc);
  #pragma unroll
  for (int mi = 0; mi < 4; mi++) {
    #pragma unroll
    for (int r = 0; r < 4; r++) {
      int ml = mb + mi * 16 + quad * 4 + r;
      if (m0 + ml < cnt) {
        int packed = toks[ml];
        int tok = packed >> 1, par = packed & 1;
        float* orow = dp + (((size_t)(ks * 2 + par) * N + tok) * C) + c0 + nb;
        #pragma unroll
        for (int ni = 0; ni < 4; ni++) orow[ni * 16 + col] = acc[mi][ni][r];
      }
    }
  }
}

__device__ __forceinline__ void run_vproj(
    const bf16* __restrict__ kkb, const bf16* __restrict__ vwb,
    float* __restrict__ vp, int n0, int c0, int ks, char* As, char* Bs) {
  GEMM_VARS
  const size_t kofs = (size_t)ks * (H / 2) * 2;
  const char* pA  = (const char*)kkb + ((size_t)(n0 + sra) * H) * 2 + kofs + scb;
  const char* pB0 = (const char*)vwb + ((size_t)(c0 + srb) * H) * 2 + kofs + scb;
  const char* pB1 = pB0 + (size_t)16 * H * 2;
  mfma_loop(pA, pB0, pB1, As, Bs, dA, dB, lane, (H / 2) / BK, mb, nb, acc);
  #pragma unroll
  for (int mi = 0; mi < 4; mi++) {
    #pragma unroll
    for (int r = 0; r < 4; r++) {
      int n = n0 + mb + mi * 16 + quad * 4 + r;
      float* orow = vp + ((size_t)ks * N + n) * C + c0 + nb;
      #pragma unroll
      for (int ni = 0; ni < 4; ni++) orow[ni * 16 + col] = acc[mi][ni][r];
    }
  }
}

// ------------------------------------------------------------ combine item
__device__ __forceinline__ void combine_item(
    int it, const float* __restrict__ dp, const float* __restrict__ vp,
    const float* __restrict__ v_b, const float* __restrict__ sg,
    const float* __restrict__ scoresums, const int* __restrict__ counts,
    float* __restrict__ out) {
  constexpr size_t NC = (size_t)N * C;
  if (it == 0 && threadIdx.x == 0) {
    float a = 0.f;
    for (int e = 0; e < 8; e++)
      a += (0.5f * (float)counts[e] * (1.f / N)) * (scoresums[e] * (1.f / N));
    out[NC] = 8.f * a * 0.01f;
  }
  size_t base = (size_t)it * 2048 + threadIdx.x;
  #pragma unroll
  for (int j = 0; j < 4; ++j) {
    size_t i = base + (size_t)j * 512;
    size_t off = i * 4;
    int n = (int)(off >> 10);
    int c = (int)(off & 1023);
    float4 a = ((const float4*)(dp))[i];
    float4 b = ((const float4*)(dp + NC))[i];
    float4 d2 = ((const float4*)(dp + 2 * NC))[i];
    float4 d3 = ((const float4*)(dp + 3 * NC))[i];
    float4 u = ((const float4*)(vp))[i];
    float4 w = ((const float4*)(vp + NC))[i];
    float4 bias = *(const float4*)(v_b + c);
    float s = sg[n];
    float4 o;
    o.x = a.x + b.x + d2.x + d3.x + s * (u.x + w.x + bias.x);
    o.y = a.y + b.y + d2.y + d3.y + s * (u.y + w.y + bias.y);
    o.z = a.z + b.z + d2.z + d3.z + s * (u.z + w.z + bias.z);
    o.w = a.w + b.w + d2.w + d3.w + s * (u.w + w.w + bias.w);
    ((float4*)out)[i] = o;
  }
}

// ================================================================ MEGA
// One persistent kernel (ordinary launch, graph-safe); 4 phases over atomic
// work queues, separated by a device-scope spin barrier. 2 stream nodes total.
__global__ __launch_bounds__(NTHR) void mega_kernel(
    const float* __restrict__ x, const float* __restrict__ gate_w,
    const float* __restrict__ sgw, const float* __restrict__ w1,
    const float* __restrict__ kw, const float* __restrict__ w2,
    const float* __restrict__ vw, const float* __restrict__ k_b,
    const float* __restrict__ v_b,
    bf16* __restrict__ xtb, float* __restrict__ rs2,
    float* __restrict__ g, float* __restrict__ sg,
    int* __restrict__ counts, int* __restrict__ lists,
    float* __restrict__ scoresums,
    bf16* __restrict__ w1b, bf16* __restrict__ kwb,
    bf16* __restrict__ w2b, bf16* __restrict__ vwb,
    bf16* __restrict__ hb, bf16* __restrict__ kkb,
    float* __restrict__ dp, float* __restrict__ vp,
    float* __restrict__ out, int* __restrict__ qc) {
  __shared__ __align__(16) char As[BM * BK * 2];   // 8 KB
  __shared__ __align__(16) char Bs[BN * BK * 2];   // 16 KB
  __shared__ int toks[BM];
  __shared__ float s_scores[8];
  __shared__ int s_cnt[8], s_base[8];
  __shared__ int s_e1[GT], s_p1[GT], s_e2[GT], s_p2[GT];
  __shared__ int s_item;
  const int tid = threadIdx.x;
  int* bar = qc + 32;                              // 3 barrier counters

  // ---------------- phase 0: gate + rmsnorm + cvt(w1,kw)
  for (;;) {
    __syncthreads();
    if (tid == 0) s_item = atomicAdd(&qc[0], 1);
    __syncthreads();
    int it = s_item;
    if (it >= P0_ITEMS) break;
    if (it < G_GATE) {
      gate_item(it, x, gate_w, sgw, g, sg, counts, lists, scoresums,
                s_scores, s_cnt, s_base, s_e1, s_p1, s_e2, s_p2);
    } else if (it < G_GATE + G_RMS) {
      rms_item(it - G_GATE, x, xtb, rs2);
    } else {
      cvt8(w1, w1b, (size_t)E * H * C / 4, kw, kwb, it - G_GATE - G_RMS);
    }
  }
  grid_barrier(&bar[0], tid);

  // ---------------- phase 1: up + kproj + cvt(w2,vw) overlapped
  for (;;) {
    __syncthreads();
    if (tid == 0) s_item = atomicAdd(&qc[1], 1);
    __syncthreads();
    int it = s_item;
    if (it >= P1_ITEMS) break;
    if (it < P1_UP) {
      int e = it >> 7, rem = it & 127;
      int h0 = (rem & 7) * BN, m0 = (rem >> 3) * BM;
      run_up(xtb, w1b, g, lists, counts, hb, e, m0, h0, As, Bs, toks);
    } else if (it < P1_UP + P1_KP) {
      int rem = it - P1_UP;
      int n0 = (rem & 15) * BM, h0 = (rem >> 4) * BN;
      run_kproj(xtb, kwb, rs2, k_b, kkb, n0, h0, As, Bs);
    } else {
      cvt8(w2, w2b, (size_t)E * C * H / 4, vw, vwb, it - P1_UP - P1_KP);
    }
  }
  grid_barrier(&bar[1], tid);

  // ---------------- phase 2: down + vproj (split-K2, atomic-free partials)
  for (;;) {
    __syncthreads();
    if (tid == 0) s_item = atomicAdd(&qc[2], 1);
    __syncthreads();
    int it = s_item;
    if (it >= P2_ITEMS) break;
    if (it < P2_DOWN) {
      int z = it >> 6, rem = it & 63;
      int e = z >> 1, ks = z & 1;
      int c0 = (rem & 3) * BN, m0 = (rem >> 2) * BM;
      run_down(hb, w2b, lists, counts, dp, e, ks, m0, c0, As, Bs, toks);
    } else {
      int rem = it - P2_DOWN;
      int ks = rem >> 6, r2 = rem & 63;
      int n0 = (r2 & 15) * BM, c0 = (r2 >> 4) * BN;
      run_vproj(kkb, vwb, vp, n0, c0, ks, As, Bs);
    }
  }
  grid_barrier(&bar[2], tid);

  // ---------------- phase 3: combine (+aux)
  for (;;) {
    __syncthreads();
    if (tid == 0) s_item = atomicAdd(&qc[3], 1);
    __syncthreads();
    int it = s_item;
    if (it >= P3_ITEMS) break;
    combine_item(it, dp, vp, v_b, sg, scoresums, counts, out);
  }
}

extern "C" void kernel_launch(void* const* d_in, const int* in_sizes, int n_in,
                              void* d_out, int out_size, void* d_ws, size_t ws_size,
                              hipStream_t stream) {
  (void)in_sizes; (void)n_in; (void)ws_size; (void)out_size;
  const float* x   = (const float*)d_in[0];
  const float* gw  = (const float*)d_in[1];
  const float* w1  = (const float*)d_in[2];
  const float* w2  = (const float*)d_in[3];
  const float* sgw = (const float*)d_in[4];
  const float* k_w = (const float*)d_in[5];
  const float* k_b = (const float*)d_in[6];
  const float* v_w = (const float*)d_in[7];
  const float* v_b = (const float*)d_in[8];
  float* out = (float*)d_out;

  // workspace layout (~116 MiB)
  char* p = (char*)d_ws;
  auto alloc = [&](size_t bytes) { char* r = p; p += (bytes + 255) & ~255ull; return r; };
  bf16* xtb  = (bf16*)alloc((size_t)N * C * 2);
  bf16* w1b  = (bf16*)alloc((size_t)E * H * C * 2);  // 32 MB; dead after phase1
  bf16* w2b  = (bf16*)alloc((size_t)E * C * H * 2);
  bf16* kwb  = (bf16*)alloc((size_t)H * C * 2);
  bf16* vwb  = (bf16*)alloc((size_t)C * H * 2);
  bf16* hb   = (bf16*)alloc((size_t)2 * N * H * 2);  // [2N][H], packed-slot rows
  bf16* kkb  = (bf16*)alloc((size_t)N * H * 2);
  float* rs2 = (float*)alloc((size_t)N * 4);
  float* g   = (float*)alloc((size_t)N * E * 4);
  float* sg  = (float*)alloc((size_t)N * 4);
  float* scoresums = (float*)alloc(256);
  int* counts = (int*)alloc(256);
  int* qc     = (int*)alloc(256);   // [0..3] queues, [32..34] barrier counters
  int* lists  = (int*)alloc((size_t)E * N * 4);
  float* vp   = (float*)alloc((size_t)2 * N * C * 4);   // 16 MB vproj partials
  float* dp   = (float*)w1b;   // 32 MB alias: [ks][par][N][C] f32 (phase2 only)

  // zero scoresums + counts + queues + barriers in one memset (contiguous)
  hipMemsetAsync(scoresums, 0, 768, stream);
  mega_kernel<<<NBLK, NTHR, 0, stream>>>(
      x, gw, sgw, w1, k_w, w2, v_w, k_b, v_b,
      xtb, rs2, g, sg, counts, lists, scoresums,
      w1b, kwb, w2b, vwb, hb, kkb, dp, vp, out, qc);
}

// Round 9
// 288.172 us; speedup vs baseline: 2.1893x; 2.1893x over previous
//
#include <hip/hip_runtime.h>
#include <hip/hip_bf16.h>
#include <stdint.h>

typedef __bf16 bf16;
typedef bf16 bf16x8 __attribute__((ext_vector_type(8)));
typedef bf16 bf16x4 __attribute__((ext_vector_type(4)));
typedef float f32x4 __attribute__((ext_vector_type(4)));

constexpr int N = 2048;   // tokens
constexpr int C = 1024;   // model dim
constexpr int H = 2048;   // hidden dim
constexpr int E = 8;      // experts
constexpr float EPS = 1.1920929e-07f;

constexpr int BM = 128, BN = 256;            // A-reuse tile, 8 waves (2Mx4N)
constexpr int GT = 32;                       // tokens per gate block
constexpr int ASUB = 128 * 64;               // one [128][32] bf16 A-subtile bytes
constexpr int BSUB = 256 * 64;               // one [256][32] bf16 B-subtile bytes

// grid decode constants
constexpr int PREP_GATE = N / GT;                       // 64
constexpr int PREP_RMS  = N;                            // 2048
constexpr int CVT_BLK   = ((E * H * C + H * C) / 4) / 1024;  // 4608 per pair
constexpr int PREP_TOTAL = PREP_GATE + PREP_RMS + 2 * CVT_BLK;

constexpr int P1_UP    = E * (N / BM) * (H / BN);       // 1024
constexpr int P1_KP    = (N / BM) * (H / BN);           // 128
constexpr int P1_TOTAL = P1_UP + P1_KP;                 // 1152

constexpr int P2_DOWN  = (E * 2) * (N / BM) * (C / BN); // 1024
constexpr int P2_VP    = (N / BM) * (C / BN) * 2;       // 128
constexpr int P2_TOTAL = P2_DOWN + P2_VP;               // 1152

constexpr int COMBINE_BLK = (N * C / 4) / 256;          // 2048

// ----------------------------------------------------- fp32->bf16 cvt helper
__device__ __forceinline__ void cvt_pair(const float* __restrict__ s1, bf16* __restrict__ d1,
                                         size_t n1, const float* __restrict__ s2,
                                         bf16* __restrict__ d2, int cbx) {
  size_t base = (size_t)cbx * 1024 + threadIdx.x;
  #pragma unroll
  for (int j = 0; j < 4; ++j) {
    size_t i = base + (size_t)j * 256;
    if (i < n1) {
      float4 v = ((const float4*)s1)[i];
      bf16x4 o = { (bf16)v.x, (bf16)v.y, (bf16)v.z, (bf16)v.w };
      ((bf16x4*)d1)[i] = o;
    } else {
      size_t k = i - n1;
      float4 v = ((const float4*)s2)[k];
      bf16x4 o = { (bf16)v.x, (bf16)v.y, (bf16)v.z, (bf16)v.w };
      ((bf16x4*)d2)[k] = o;
    }
  }
}

// ====================================================================== PREP
// [0,64): gate (NO LDS -> cvt blocks get full occupancy; gate_w via L2)
// [64,2112): rmsnorm   [2112,6720): cvt w1+kw   [6720,11328): cvt w2+vw
__global__ __launch_bounds__(256) void prep_kernel(
    const float* __restrict__ x, const float* __restrict__ gate_w,
    const float* __restrict__ sgw, const float* __restrict__ w1,
    const float* __restrict__ kw, const float* __restrict__ w2,
    const float* __restrict__ vw,
    bf16* __restrict__ xtb, float* __restrict__ rs2_arr,
    float* __restrict__ g, float* __restrict__ sgbuf,
    int* __restrict__ counts, int* __restrict__ lists,
    float* __restrict__ scoresums,
    bf16* __restrict__ w1b, bf16* __restrict__ kwb,
    bf16* __restrict__ w2b, bf16* __restrict__ vwb) {
  __shared__ float s_scores[8];
  __shared__ int   s_cnt[8];
  __shared__ int   s_base[8];
  __shared__ int   s_e1[GT], s_p1[GT], s_e2[GT], s_p2[GT];
  __shared__ float red[4];
  __shared__ float tot;
  const int bx = blockIdx.x;
  const int tid = threadIdx.x, lane = tid & 63, wave = tid >> 6;

  if (bx >= PREP_GATE + PREP_RMS + CVT_BLK) {  // ---- cvt w2 + v_w
    cvt_pair(w2, w2b, (size_t)E * C * H / 4, vw, vwb,
             bx - PREP_GATE - PREP_RMS - CVT_BLK);
    return;
  }
  if (bx >= PREP_GATE + PREP_RMS) {            // ---- cvt w1 + k_w
    cvt_pair(w1, w1b, (size_t)E * H * C / 4, kw, kwb, bx - PREP_GATE - PREP_RMS);
    return;
  }
  if (bx >= PREP_GATE) {                       // ---- rmsnorm token row
    int n = bx - PREP_GATE;
    float4 v = ((const float4*)(x + (size_t)n * C))[tid];
    float ss = v.x*v.x + v.y*v.y + v.z*v.z + v.w*v.w;
    #pragma unroll
    for (int off = 32; off > 0; off >>= 1) ss += __shfl_down(ss, off, 64);
    if (lane == 0) red[wave] = ss;
    __syncthreads();
    if (tid == 0) tot = red[0] + red[1] + red[2] + red[3];
    __syncthreads();
    float sumsq = tot;
    float rs1 = rsqrtf(sumsq * (1.f / C) + EPS);
    bf16x4 o = { (bf16)(v.x*rs1), (bf16)(v.y*rs1), (bf16)(v.z*rs1), (bf16)(v.w*rs1) };
    ((bf16x4*)(xtb + (size_t)n * C))[tid] = o;
    if (tid == 0) {
      float m2 = sumsq * rs1 * rs1 * (1.f / C);  // mean(xt^2) exactly
      rs2_arr[n] = rsqrtf(m2 + EPS);
    }
    return;
  }
  // --------------------------------------------------------------- gate
  if (tid < 8) { s_scores[tid] = 0.f; s_cnt[tid] = 0; }
  __syncthreads();

  const int tok0 = bx * GT + wave * (GT / 4);
  for (int tt = 0; tt < GT / 4; ++tt) {
    const int tok = tok0 + tt;
    const float* xr = x + (size_t)tok * C;
    float acc[10];
    #pragma unroll
    for (int e = 0; e < 10; e++) acc[e] = 0.f;
    #pragma unroll
    for (int k = 0; k < 16; ++k) {
      int c = k * 64 + lane;
      float xv = xr[c];
      #pragma unroll
      for (int e = 0; e < 8; e++) acc[e] = fmaf(xv, gate_w[e * 1024 + c], acc[e]);
      acc[8] = fmaf(xv, sgw[c], acc[8]);
      acc[9] = fmaf(xv, xv, acc[9]);           // sum(x^2) for self rs1
    }
    #pragma unroll
    for (int e = 0; e < 10; e++) {
      float v = acc[e];
      #pragma unroll
      for (int off = 32; off > 0; off >>= 1) v += __shfl_xor(v, off, 64);
      acc[e] = v;
    }
    if (lane == 0) {
      float rs1 = rsqrtf(acc[9] * (1.f / C) + EPS);
      float raw[9];
      #pragma unroll
      for (int e = 0; e < 9; e++) raw[e] = acc[e] * rs1;
      float m = raw[0];
      for (int e = 1; e < 8; e++) m = fmaxf(m, raw[e]);
      float sc[8], s = 0.f;
      for (int e = 0; e < 8; e++) { sc[e] = expf(raw[e] - m); s += sc[e]; }
      float inv = 1.f / s;
      for (int e = 0; e < 8; e++) sc[e] *= inv;
      int i1 = 0;
      for (int e = 1; e < 8; e++) if (sc[e] > sc[i1]) i1 = e;
      int i2 = -1;
      for (int e = 0; e < 8; e++) {
        if (e == i1) continue;
        if (i2 < 0 || sc[e] > sc[i2]) i2 = e;
      }
      float denom = sc[i1] + sc[i2] + 1e-6f;
      float* gr = g + (size_t)tok * E;
      #pragma unroll
      for (int e = 0; e < 8; e++) gr[e] = 0.f;
      gr[i1] = sc[i1] / denom;
      gr[i2] = sc[i2] / denom;
      sgbuf[tok] = 1.f / (1.f + expf(-raw[8]));
      for (int e = 0; e < 8; e++) atomicAdd(&s_scores[e], sc[e]);  // LDS
      int lt = wave * (GT / 4) + tt;
      int p1 = atomicAdd(&s_cnt[i1], 1);   // LDS
      int p2 = atomicAdd(&s_cnt[i2], 1);   // LDS
      s_e1[lt] = i1; s_p1[lt] = p1;
      s_e2[lt] = i2; s_p2[lt] = p2;
    }
  }
  __syncthreads();
  if (tid < 8) {
    s_base[tid] = atomicAdd(&counts[tid], s_cnt[tid]);   // 8 global atomics
    atomicAdd(&scoresums[tid], s_scores[tid]);           // 8 global atomics
  }
  __syncthreads();
  if (tid < GT) {
    int tok = bx * GT + tid;
    int e1 = s_e1[tid], e2 = s_e2[tid];
    lists[e1 * N + s_base[e1] + s_p1[tid]] = (tok << 1);
    lists[e2 * N + s_base[e2] + s_p2[tid]] = (tok << 1) | 1;
  }
}

// -------------------------------------------------------- MFMA GEMM mainloop
// R9 (round-4, best measured): 128x256 tile, 8 waves (2Mx4N), BK=64 as 2x32
// subtiles, single-buffer, all staging via global_load_lds from bf16 buffers.
#define GLL(gp, lp)                                                             \
  __builtin_amdgcn_global_load_lds((__attribute__((address_space(1))) void*)(gp), \
                                   (__attribute__((address_space(3))) void*)(lp), 16, 0, 0)

__device__ __forceinline__ void mfma_loop(
    const char* pA, const char* pB0, const char* pB1,
    char* As, char* Bs, int dA, int dB0, int dB1,
    int lane, int kIters, int mb, int nb, f32x4 acc[4][4]) {
  const int arow = lane & 15;
  const int koff = (lane >> 4) * 16;            // quad*8 elems * 2B
  for (int kt = 0; kt < kIters; ++kt) {
    GLL(pA,       As + dA);          GLL(pA  + 64, As + ASUB + dA);
    GLL(pB0,      Bs + dB0);         GLL(pB0 + 64, Bs + BSUB + dB0);
    GLL(pB1,      Bs + dB1);         GLL(pB1 + 64, Bs + BSUB + dB1);
    pA += 128; pB0 += 128; pB1 += 128;          // advance K by 64 elems
    __syncthreads();
    #pragma unroll
    for (int kh = 0; kh < 2; ++kh) {
      const char* Ac = As + kh * ASUB;
      const char* Bc = Bs + kh * BSUB;
      bf16x8 a[4], b[4];
      #pragma unroll
      for (int i = 0; i < 4; ++i) {
        a[i] = *(const bf16x8*)(Ac + (mb + i * 16 + arow) * 64 + koff);
        b[i] = *(const bf16x8*)(Bc + (nb + i * 16 + arow) * 64 + koff);
      }
      #pragma unroll
      for (int i = 0; i < 4; ++i)
        #pragma unroll
        for (int j = 0; j < 4; ++j)
          acc[i][j] = __builtin_amdgcn_mfma_f32_16x16x32_bf16(a[i], b[j], acc[i][j], 0, 0, 0);
    }
    __syncthreads();
  }
}

#define GEMM_VARS                                                  \
  const int tid = threadIdx.x;                                     \
  const int lane = tid & 63, wave = tid >> 6;  /* 0..7 */          \
  const int mb = (wave >> 2) * 64, nb = (wave & 3) * 64;           \
  const int srow = wave * 16 + (lane >> 2);    /* staging row */   \
  const int scb = (lane & 3) * 16;             /* staging col B */ \
  const int dA  = wave * 1024;                 /* LDS dests */     \
  const int dB0 = wave * 1024;                                     \
  const int dB1 = 8192 + wave * 1024;                              \
  const int col = lane & 15, quad = lane >> 4;                     \
  f32x4 acc[4][4] = {};

// ---------------------------------------------------------------- GEMM bodies
__device__ __forceinline__ void run_up(
    const bf16* __restrict__ xtb, const bf16* __restrict__ w1b,
    const float* __restrict__ g, const int* __restrict__ lists,
    const int* __restrict__ counts, bf16* __restrict__ hb,
    int e, int m0, int h0, char* As, char* Bs, int* toks) {
  const int cnt = counts[e];
  if (m0 >= cnt) return;
  GEMM_VARS
  if (tid < BM) toks[tid] = lists[e * N + min(m0 + tid, cnt - 1)];
  __syncthreads();
  const char* pA  = (const char*)xtb + ((size_t)(toks[srow] >> 1) * C) * 2 + scb;
  const char* pB0 = (const char*)w1b + ((size_t)e * H * C + (size_t)(h0 + srow) * C) * 2 + scb;
  const char* pB1 = (const char*)w1b + ((size_t)e * H * C + (size_t)(h0 + 128 + srow) * C) * 2 + scb;
  mfma_loop(pA, pB0, pB1, As, Bs, dA, dB0, dB1, lane, C / 64, mb, nb, acc);
  #pragma unroll
  for (int mi = 0; mi < 4; mi++) {
    #pragma unroll
    for (int r = 0; r < 4; r++) {
      int ml = mb + mi * 16 + quad * 4 + r;
      if (m0 + ml < cnt) {
        int packed = toks[ml];
        float gv = g[(size_t)(packed >> 1) * E + e];
        size_t base = (size_t)packed * H + h0 + nb;
        #pragma unroll
        for (int ni = 0; ni < 4; ni++) {
          float v = fmaxf(acc[mi][ni][r], 0.f);
          hb[base + ni * 16 + col] = (bf16)(v * v * gv);
        }
      }
    }
  }
}

__device__ __forceinline__ void run_kproj(
    const bf16* __restrict__ xtb, const bf16* __restrict__ kwb,
    const float* __restrict__ rs2, const float* __restrict__ k_b,
    bf16* __restrict__ kkb, int n0, int h0, char* As, char* Bs) {
  GEMM_VARS
  const char* pA  = (const char*)xtb + ((size_t)(n0 + srow) * C) * 2 + scb;
  const char* pB0 = (const char*)kwb + ((size_t)(h0 + srow) * C) * 2 + scb;
  const char* pB1 = (const char*)kwb + ((size_t)(h0 + 128 + srow) * C) * 2 + scb;
  mfma_loop(pA, pB0, pB1, As, Bs, dA, dB0, dB1, lane, C / 64, mb, nb, acc);
  #pragma unroll
  for (int mi = 0; mi < 4; mi++) {
    #pragma unroll
    for (int r = 0; r < 4; r++) {
      int n = n0 + mb + mi * 16 + quad * 4 + r;
      float rs = rs2[n];
      #pragma unroll
      for (int ni = 0; ni < 4; ni++) {
        int h = h0 + nb + ni * 16 + col;
        float v = fmaf(acc[mi][ni][r], rs, k_b[h]);
        v = fmaxf(v, 0.f);
        kkb[(size_t)n * H + h] = (bf16)(v * v);
      }
    }
  }
}

// down: plain f32 stores into per-(ks,parity) partials; one writer per elem.
__device__ __forceinline__ void run_down(
    const bf16* __restrict__ hb, const bf16* __restrict__ w2b,
    const int* __restrict__ lists, const int* __restrict__ counts,
    float* __restrict__ dp, int e, int ks, int m0, int c0,
    char* As, char* Bs, int* toks) {
  const int cnt = counts[e];
  if (m0 >= cnt) return;
  GEMM_VARS
  if (tid < BM) toks[tid] = lists[e * N + min(m0 + tid, cnt - 1)];
  __syncthreads();
  const size_t kofs = (size_t)ks * (H / 2) * 2;   // byte offset into K
  const char* pA  = (const char*)hb + ((size_t)toks[srow] * H) * 2 + kofs + scb;
  const char* pB0 = (const char*)w2b + ((size_t)e * C * H + (size_t)(c0 + srow) * H) * 2 + kofs + scb;
  const char* pB1 = (const char*)w2b + ((size_t)e * C * H + (size_t)(c0 + 128 + srow) * H) * 2 + kofs + scb;
  mfma_loop(pA, pB0, pB1, As, Bs, dA, dB0, dB1, lane, (H / 2) / 64, mb, nb, acc);
  #pragma unroll
  for (int mi = 0; mi < 4; mi++) {
    #pragma unroll
    for (int r = 0; r < 4; r++) {
      int ml = mb + mi * 16 + quad * 4 + r;
      if (m0 + ml < cnt) {
        int packed = toks[ml];
        int tok = packed >> 1, par = packed & 1;
        float* orow = dp + (((size_t)(ks * 2 + par) * N + tok) * C) + c0 + nb;
        #pragma unroll
        for (int ni = 0; ni < 4; ni++) orow[ni * 16 + col] = acc[mi][ni][r];
      }
    }
  }
}

// vproj: raw GEMM partial per ks -> plain stores, one writer.
__device__ __forceinline__ void run_vproj(
    const bf16* __restrict__ kkb, const bf16* __restrict__ vwb,
    float* __restrict__ vp, int n0, int c0, int ks, char* As, char* Bs) {
  GEMM_VARS
  const size_t kofs = (size_t)ks * (H / 2) * 2;
  const char* pA  = (const char*)kkb + ((size_t)(n0 + srow) * H) * 2 + kofs + scb;
  const char* pB0 = (const char*)vwb + ((size_t)(c0 + srow) * H) * 2 + kofs + scb;
  const char* pB1 = (const char*)vwb + ((size_t)(c0 + 128 + srow) * H) * 2 + kofs + scb;
  mfma_loop(pA, pB0, pB1, As, Bs, dA, dB0, dB1, lane, (H / 2) / 64, mb, nb, acc);
  #pragma unroll
  for (int mi = 0; mi < 4; mi++) {
    #pragma unroll
    for (int r = 0; r < 4; r++) {
      int n = n0 + mb + mi * 16 + quad * 4 + r;
      float* orow = vp + ((size_t)ks * N + n) * C + c0 + nb;
      #pragma unroll
      for (int ni = 0; ni < 4; ni++) orow[ni * 16 + col] = acc[mi][ni][r];
    }
  }
}

// ==================================================================== PHASE 1
// bx [0,1024): up   [1024,1152): kproj
__global__ __launch_bounds__(512) void phase1_kernel(
    const bf16* __restrict__ xtb, const bf16* __restrict__ w1b,
    const float* __restrict__ g, const int* __restrict__ lists,
    const int* __restrict__ counts, bf16* __restrict__ hb,
    const bf16* __restrict__ kwb, const float* __restrict__ rs2,
    const float* __restrict__ k_b, bf16* __restrict__ kkb) {
  __shared__ __align__(16) char As[2 * ASUB];   // 16 KB
  __shared__ __align__(16) char Bs[2 * BSUB];   // 32 KB
  __shared__ int toks[BM];
  const int bx = blockIdx.x;
  if (bx < P1_UP) {
    int e = bx >> 7, rem = bx & 127;
    int h0 = (rem & 7) * BN, m0 = (rem >> 3) * BM;
    run_up(xtb, w1b, g, lists, counts, hb, e, m0, h0, As, Bs, toks);
  } else {
    int rem = bx - P1_UP;
    int n0 = (rem & 15) * BM, h0 = (rem >> 4) * BN;
    run_kproj(xtb, kwb, rs2, k_b, kkb, n0, h0, As, Bs);
  }
}

// ==================================================================== PHASE 2
// bx [0,1024): down (split-K2)   [1024,1152): vproj (split-K2)
__global__ __launch_bounds__(512) void phase2_kernel(
    const bf16* __restrict__ hb, const bf16* __restrict__ w2b,
    const int* __restrict__ lists, const int* __restrict__ counts,
    const bf16* __restrict__ kkb, const bf16* __restrict__ vwb,
    float* __restrict__ dp, float* __restrict__ vp) {
  __shared__ __align__(16) char As[2 * ASUB];
  __shared__ __align__(16) char Bs[2 * BSUB];
  __shared__ int toks[BM];
  const int bx = blockIdx.x;
  if (bx < P2_DOWN) {
    int z = bx >> 6, rem = bx & 63;
    int e = z >> 1, ks = z & 1;
    int c0 = (rem & 3) * BN, m0 = (rem >> 2) * BM;
    run_down(hb, w2b, lists, counts, dp, e, ks, m0, c0, As, Bs, toks);
  } else {
    int rem = bx - P2_DOWN;
    int ks = rem >> 6, r2 = rem & 63;
    int n0 = (r2 & 15) * BM, c0 = (r2 >> 4) * BN;
    run_vproj(kkb, vwb, vp, n0, c0, ks, As, Bs);
  }
}

// ================================================================== COMBINE
// out[n][c] = sum_ks,par dp + sg[n] * (vp0 + vp1 + v_b[c]);   + aux in block 0
__global__ __launch_bounds__(256) void combine_kernel(
    const float* __restrict__ dp, const float* __restrict__ vp,
    const float* __restrict__ v_b, const float* __restrict__ sg,
    const float* __restrict__ scoresums, const int* __restrict__ counts,
    float* __restrict__ out) {
  constexpr size_t NC = (size_t)N * C;
  if (blockIdx.x == 0 && threadIdx.x == 0) {
    float a = 0.f;
    for (int e = 0; e < 8; e++)
      a += (0.5f * (float)counts[e] * (1.f / N)) * (scoresums[e] * (1.f / N));
    out[NC] = 8.f * a * 0.01f;
  }
  size_t i = (size_t)blockIdx.x * 256 + threadIdx.x;   // float4 index
  size_t off = i * 4;
  int n = (int)(off >> 10);                            // C = 1024
  int c = (int)(off & 1023);
  float4 a = ((const float4*)(dp))[i];
  float4 b = ((const float4*)(dp + NC))[i];
  float4 d2 = ((const float4*)(dp + 2 * NC))[i];
  float4 d3 = ((const float4*)(dp + 3 * NC))[i];
  float4 u = ((const float4*)(vp))[i];
  float4 w = ((const float4*)(vp + NC))[i];
  float4 bias = *(const float4*)(v_b + c);
  float s = sg[n];
  float4 o;
  o.x = a.x + b.x + d2.x + d3.x + s * (u.x + w.x + bias.x);
  o.y = a.y + b.y + d2.y + d3.y + s * (u.y + w.y + bias.y);
  o.z = a.z + b.z + d2.z + d3.z + s * (u.z + w.z + bias.z);
  o.w = a.w + b.w + d2.w + d3.w + s * (u.w + w.w + bias.w);
  ((float4*)out)[i] = o;
}

extern "C" void kernel_launch(void* const* d_in, const int* in_sizes, int n_in,
                              void* d_out, int out_size, void* d_ws, size_t ws_size,
                              hipStream_t stream) {
  (void)in_sizes; (void)n_in; (void)ws_size; (void)out_size;
  const float* x   = (const float*)d_in[0];
  const float* gw  = (const float*)d_in[1];
  const float* w1  = (const float*)d_in[2];
  const float* w2  = (const float*)d_in[3];
  const float* sgw = (const float*)d_in[4];
  const float* k_w = (const float*)d_in[5];
  const float* k_b = (const float*)d_in[6];
  const float* v_w = (const float*)d_in[7];
  const float* v_b = (const float*)d_in[8];
  float* out = (float*)d_out;

  // workspace layout (~116 MiB)
  char* p = (char*)d_ws;
  auto alloc = [&](size_t bytes) { char* r = p; p += (bytes + 255) & ~255ull; return r; };
  bf16* xtb  = (bf16*)alloc((size_t)N * C * 2);
  bf16* w1b  = (bf16*)alloc((size_t)E * H * C * 2);  // 32 MB; dead after phase1
  bf16* w2b  = (bf16*)alloc((size_t)E * C * H * 2);
  bf16* kwb  = (bf16*)alloc((size_t)H * C * 2);
  bf16* vwb  = (bf16*)alloc((size_t)C * H * 2);
  bf16* hb   = (bf16*)alloc((size_t)2 * N * H * 2);  // [2N][H], packed-slot rows
  bf16* kkb  = (bf16*)alloc((size_t)N * H * 2);
  float* rs2 = (float*)alloc((size_t)N * 4);
  float* g   = (float*)alloc((size_t)N * E * 4);
  float* sg  = (float*)alloc((size_t)N * 4);
  float* scoresums = (float*)alloc(256);             // +counts in next 256B slot
  int* counts = (int*)alloc(256);
  int* lists  = (int*)alloc((size_t)E * N * 4);
  float* vp   = (float*)alloc((size_t)2 * N * C * 4);   // 16 MB vproj partials
  float* dp   = (float*)w1b;   // 32 MB alias: [ks][par][N][C] f32, exact fit

  hipMemsetAsync(scoresums, 0, 512, stream);         // covers scoresums + counts
  prep_kernel<<<PREP_TOTAL, 256, 0, stream>>>(
      x, gw, sgw, w1, k_w, w2, v_w, xtb, rs2, g, sg, counts, lists, scoresums,
      w1b, kwb, w2b, vwb);
  phase1_kernel<<<P1_TOTAL, 512, 0, stream>>>(
      xtb, w1b, g, lists, counts, hb, kwb, rs2, k_b, kkb);
  phase2_kernel<<<P2_TOTAL, 512, 0, stream>>>(
      hb, w2b, lists, counts, kkb, vwb, dp, vp);
  combine_kernel<<<COMBINE_BLK, 256, 0, stream>>>(
      dp, vp, v_b, sg, scoresums, counts, out);
}